// Round 1
// baseline (1193.097 us; speedup 1.0000x reference)
//
#include <hip/hip_runtime.h>

#define MIN_PTS 4
#define H1 64
#define H2 128
#define OUTF 256

__global__ __launch_bounds__(256) void refine_kernel(
    const float* __restrict__ points,    // [P][N][3]
    const int*   __restrict__ lengths,   // [P]
    const float* __restrict__ proposals, // [P][6]
    const float* __restrict__ W1, const float* __restrict__ b1,   // [3][64],[64]
    const float* __restrict__ W2, const float* __restrict__ b2,   // [64][128],[128]
    const float* __restrict__ W3, const float* __restrict__ b3,   // [128][256],[256]
    const float* __restrict__ Wc, const float* __restrict__ bc,   // [256][1],[1]
    const float* __restrict__ Wr, const float* __restrict__ br,   // [256][4],[4]
    float* __restrict__ out, int P, int N)
{
    const int p   = blockIdx.x;
    const int tid = threadIdx.x;
    const int len = lengths[p];

    // Invalid proposal: feats == 0 -> outputs are just the biases.
    if (len < MIN_PTS) {
        if (tid == 0) {
            out[p] = bc[0];
            out[P + p * 4 + 0] = br[0];
            out[P + p * 4 + 1] = br[1];
            out[P + p * 4 + 2] = br[2];
            out[P + p * 4 + 3] = br[3];
        }
        return;
    }

    __shared__ float h1s[H1 * 256];   // h1s[k*256 + tid], stride 256 -> 2 lanes/bank (free)
    __shared__ int   feats_i[OUTF];   // max-pooled features as int bits (all values >= 0)

    // init feats (256 threads, 256 feats)
    feats_i[tid] = 0;
    __syncthreads();

    const int L    = len;                 // len >= MIN_PTS >= 1
    const int nact = (L + 63) & ~63;      // round up to wave multiple -> wave-uniform branch

    if (tid < nact) {
        const int jj = min(tid, L - 1);   // duplicates of last point don't change the max

        // local coords
        const float px = points[(p * N + jj) * 3 + 0];
        const float py = points[(p * N + jj) * 3 + 1];
        const float pz = points[(p * N + jj) * 3 + 2];
        const float cx = proposals[p * 6 + 0];
        const float cy = proposals[p * 6 + 1];
        const float cz = proposals[p * 6 + 2];
        const float hx = fmaf(proposals[p * 6 + 3], 0.5f, 1e-6f);
        const float hy = fmaf(proposals[p * 6 + 4], 0.5f, 1e-6f);
        const float hz = fmaf(proposals[p * 6 + 5], 0.5f, 1e-6f);
        const float x0 = (px - cx) / hx;
        const float x1 = (py - cy) / hy;
        const float x2 = (pz - cz) / hz;

        // ---- layer 1: 3 -> 64, relu, park in LDS ----
        #pragma unroll
        for (int f = 0; f < H1; ++f) {
            float v = fmaf(x0, W1[f], fmaf(x1, W1[H1 + f], fmaf(x2, W1[2 * H1 + f], b1[f])));
            h1s[f * 256 + tid] = fmaxf(v, 0.0f);
        }

        // ---- layer 2: 64 -> 128, h2 in registers ----
        float h2[H2];
        #pragma unroll
        for (int f = 0; f < H2; ++f) h2[f] = b2[f];

        #pragma unroll 2
        for (int k = 0; k < H1; ++k) {
            const float a = h1s[k * 256 + tid];
            const float* __restrict__ w = &W2[k * H2];
            #pragma unroll
            for (int f = 0; f < H2; ++f) h2[f] = fmaf(a, w[f], h2[f]);
        }
        #pragma unroll
        for (int f = 0; f < H2; ++f) h2[f] = fmaxf(h2[f], 0.0f);

        // ---- layer 3: 128 -> 256 in chunks of 8, fused max-pool ----
        #pragma unroll 1
        for (int f0 = 0; f0 < OUTF; f0 += 8) {
            float acc[8];
            #pragma unroll
            for (int i = 0; i < 8; ++i) acc[i] = b3[f0 + i];

            #pragma unroll
            for (int k = 0; k < H2; ++k) {
                const float a = h2[k];
                #pragma unroll
                for (int i = 0; i < 8; ++i)
                    acc[i] = fmaf(a, W3[k * OUTF + f0 + i], acc[i]);
            }
            #pragma unroll
            for (int i = 0; i < 8; ++i) acc[i] = fmaxf(acc[i], 0.0f);

            // butterfly max over the 64-lane wave
            #pragma unroll
            for (int off = 32; off > 0; off >>= 1) {
                #pragma unroll
                for (int i = 0; i < 8; ++i)
                    acc[i] = fmaxf(acc[i], __shfl_xor(acc[i], off, 64));
            }
            // one lane per wave merges into LDS (non-negative floats: int-bit max is exact)
            if ((tid & 63) == 0) {
                #pragma unroll
                for (int i = 0; i < 8; ++i)
                    atomicMax(&feats_i[f0 + i], __float_as_int(acc[i]));
            }
        }
    }
    __syncthreads();

    // ---- heads: wave 0 computes 5 dot products of length 256 ----
    if (tid < 64) {
        float c = 0.0f, r0 = 0.0f, r1 = 0.0f, r2 = 0.0f, r3 = 0.0f;
        #pragma unroll
        for (int t = 0; t < 4; ++t) {
            const int f = tid + 64 * t;
            const float v = __int_as_float(feats_i[f]);
            c  = fmaf(v, Wc[f], c);
            r0 = fmaf(v, Wr[f * 4 + 0], r0);
            r1 = fmaf(v, Wr[f * 4 + 1], r1);
            r2 = fmaf(v, Wr[f * 4 + 2], r2);
            r3 = fmaf(v, Wr[f * 4 + 3], r3);
        }
        #pragma unroll
        for (int off = 32; off > 0; off >>= 1) {
            c  += __shfl_xor(c,  off, 64);
            r0 += __shfl_xor(r0, off, 64);
            r1 += __shfl_xor(r1, off, 64);
            r2 += __shfl_xor(r2, off, 64);
            r3 += __shfl_xor(r3, off, 64);
        }
        if (tid == 0) {
            out[p]             = c  + bc[0];
            out[P + p * 4 + 0] = r0 + br[0];
            out[P + p * 4 + 1] = r1 + br[1];
            out[P + p * 4 + 2] = r2 + br[2];
            out[P + p * 4 + 3] = r3 + br[3];
        }
    }
}

extern "C" void kernel_launch(void* const* d_in, const int* in_sizes, int n_in,
                              void* d_out, int out_size, void* d_ws, size_t ws_size,
                              hipStream_t stream)
{
    const float* points    = (const float*)d_in[0];
    const int*   lengths   = (const int*)  d_in[1];
    const float* proposals = (const float*)d_in[2];
    const float* W1 = (const float*)d_in[3];
    const float* b1 = (const float*)d_in[4];
    const float* W2 = (const float*)d_in[5];
    const float* b2 = (const float*)d_in[6];
    const float* W3 = (const float*)d_in[7];
    const float* b3 = (const float*)d_in[8];
    const float* Wc = (const float*)d_in[9];
    const float* bc = (const float*)d_in[10];
    const float* Wr = (const float*)d_in[11];
    const float* br = (const float*)d_in[12];
    float* out = (float*)d_out;

    const int P = in_sizes[1];              // 2048
    const int N = in_sizes[0] / (3 * P);    // 256

    refine_kernel<<<dim3(P), dim3(256), 0, stream>>>(
        points, lengths, proposals, W1, b1, W2, b2, W3, b3, Wc, bc, Wr, br,
        out, P, N);
}

// Round 2
// 88.071 us; speedup vs baseline: 13.5470x; 13.5470x over previous
//
#include <hip/hip_runtime.h>

#define MIN_PTS 4

typedef short bf16x8 __attribute__((ext_vector_type(8)));
typedef float f32x4  __attribute__((ext_vector_type(4)));

__device__ __forceinline__ ushort f2bf(float x) {
    unsigned u = __float_as_uint(x);
    u = (u + 0x7fffu + ((u >> 16) & 1u)) >> 16;   // RNE, finite inputs
    return (ushort)u;
}

// Pack W2 [64][128] and W3 [128][256] (fp32 row-major, K x N) into bf16
// MFMA B-fragment-linear layout: [ntile][kstep][lane][8], where
// element j of lane l = W[k = 32*ks + 8*(l>>4) + j][col = 16*nt + (l&15)].
__global__ void pack_weights(const float* __restrict__ W2, const float* __restrict__ W3,
                             ushort* __restrict__ B2P, ushort* __restrict__ B3P)
{
    int idx = blockIdx.x * 256 + threadIdx.x;
    if (idx < 8192) {   // W2: 8 ntiles x 2 ksteps x 64 lanes x 8
        int j = idx & 7, l = (idx >> 3) & 63, ks = (idx >> 9) & 1, nt = idx >> 10;
        int k   = ks * 32 + (l >> 4) * 8 + j;
        int col = nt * 16 + (l & 15);
        B2P[idx] = f2bf(W2[k * 128 + col]);
    }
    if (idx < 32768) {  // W3: 16 ntiles x 4 ksteps x 64 lanes x 8
        int j = idx & 7, l = (idx >> 3) & 63, ks = (idx >> 9) & 3, nt = idx >> 11;
        int k   = ks * 32 + (l >> 4) * 8 + j;
        int col = nt * 16 + (l & 15);
        B3P[idx] = f2bf(W3[k * 256 + col]);
    }
}

__global__ __launch_bounds__(256) void refine_mfma(
    const float* __restrict__ points,    // [P][N][3]
    const int*   __restrict__ lengths,   // [P]
    const float* __restrict__ proposals, // [P][6]
    const float* __restrict__ W1, const float* __restrict__ b1,   // [3][64],[64]
    const float* __restrict__ b2,                                  // [128]
    const float* __restrict__ b3,                                  // [256]
    const float* __restrict__ Wc, const float* __restrict__ bc,   // [256][1],[1]
    const float* __restrict__ Wr, const float* __restrict__ br,   // [256][4],[4]
    const ushort* __restrict__ B2P, const ushort* __restrict__ B3P,
    float* __restrict__ out, int P, int N)
{
    const int p   = blockIdx.x;
    const int tid = threadIdx.x;
    const int len = lengths[p];

    if (len < MIN_PTS) {
        if (tid == 0) {
            out[p] = bc[0];
            out[P + p * 4 + 0] = br[0];
            out[P + p * 4 + 1] = br[1];
            out[P + p * 4 + 2] = br[2];
            out[P + p * 4 + 3] = br[3];
        }
        return;
    }

    // A1: h1 fragments  [mtile(4)][kstep(2)][lane(64)][8] bf16  = 8 KB
    // A3: h2 fragments  [mtile(4)][kstep(4)][lane(64)][8] bf16  = 16 KB
    __shared__ __align__(16) ushort A1[4096];
    __shared__ __align__(16) ushort A3[8192];
    __shared__ float featsS[256];

    const int lane = tid & 63;
    const int w    = tid >> 6;      // wave id 0..3
    const int rc   = lane & 15;
    const int g    = lane >> 4;

    // proposal params
    const float cx = proposals[p * 6 + 0];
    const float cy = proposals[p * 6 + 1];
    const float cz = proposals[p * 6 + 2];
    const float hx = fmaf(proposals[p * 6 + 3], 0.5f, 1e-6f);
    const float hy = fmaf(proposals[p * 6 + 4], 0.5f, 1e-6f);
    const float hz = fmaf(proposals[p * 6 + 5], 0.5f, 1e-6f);

    // hoisted biases (per-lane)
    float bias2[2][4];
    #pragma unroll
    for (int nt = 0; nt < 2; ++nt)
        #pragma unroll
        for (int rr = 0; rr < 4; ++rr)
            bias2[nt][rr] = b2[32 * w + 16 * nt + 4 * g + rr];
    float bias3v[4];
    #pragma unroll
    for (int nt = 0; nt < 4; ++nt)
        bias3v[nt] = b3[64 * w + 16 * nt + rc];

    float pool[4] = {0.f, 0.f, 0.f, 0.f};

    const int L = len;
    const int S = (L + 63) >> 6;    // stripes of 64 points

    #pragma unroll 1
    for (int s = 0; s < S; ++s) {
        // ---------- Phase A: layer 1 (3->64) on VALU, write A1 fragments ----------
        {
            const int jg = s * 64 + lane;           // point slot
            const int jj = min(jg, L - 1);          // duplicate last point (max-safe)
            const float* pt = points + (p * N + jj) * 3;
            const float x0 = (pt[0] - cx) / hx;
            const float x1 = (pt[1] - cy) / hy;
            const float x2 = (pt[2] - cz) / hz;

            union { ushort u[16]; uint4 q[2]; } t;
            #pragma unroll
            for (int i = 0; i < 16; ++i) {
                const int f = w * 16 + i;           // wave w computes features 16w..16w+15
                float v = fmaf(x0, W1[f], fmaf(x1, W1[64 + f], fmaf(x2, W1[128 + f], b1[f])));
                t.u[i] = f2bf(fmaxf(v, 0.f));
            }
            const int mt = lane >> 4, r = lane & 15;
            #pragma unroll
            for (int c = 0; c < 2; ++c) {
                const int k0 = w * 16 + c * 8;
                const int ks = k0 >> 5, g2 = (k0 >> 3) & 3;
                const int chunk = (mt * 2 + ks) * 64 + g2 * 16 + r;
                *(uint4*)&A1[chunk * 8] = t.q[c];
            }
        }
        __syncthreads();   // A1 ready; prev stripe's A3 reads done

        // ---------- Phase B: layer 2 (64->128), swapped operands ----------
        // D[f][point] tile: Arg1 = W2^T frag (B2P), Arg2 = h1 frag (A1)
        f32x4 acc2[4][2];
        #pragma unroll
        for (int mt = 0; mt < 4; ++mt)
            #pragma unroll
            for (int nt = 0; nt < 2; ++nt)
                acc2[mt][nt] = (f32x4){0.f, 0.f, 0.f, 0.f};

        #pragma unroll
        for (int ks = 0; ks < 2; ++ks) {
            const bf16x8 bw0 = *(const bf16x8*)(B2P + (((2 * w + 0) * 2 + ks) * 64 + lane) * 8);
            const bf16x8 bw1 = *(const bf16x8*)(B2P + (((2 * w + 1) * 2 + ks) * 64 + lane) * 8);
            #pragma unroll
            for (int mt = 0; mt < 4; ++mt) {
                const bf16x8 a = *(const bf16x8*)&A1[((mt * 2 + ks) * 64 + lane) * 8];
                acc2[mt][0] = __builtin_amdgcn_mfma_f32_16x16x32_bf16(bw0, a, acc2[mt][0], 0, 0, 0);
                acc2[mt][1] = __builtin_amdgcn_mfma_f32_16x16x32_bf16(bw1, a, acc2[mt][1], 0, 0, 0);
            }
        }
        // bias+relu, pack 4 consecutive k-features of one point -> ds_write_b64 into A3
        #pragma unroll
        for (int mt = 0; mt < 4; ++mt)
            #pragma unroll
            for (int nt = 0; nt < 2; ++nt) {
                const uint u0 = (uint)f2bf(fmaxf(acc2[mt][nt][0] + bias2[nt][0], 0.f))
                              | ((uint)f2bf(fmaxf(acc2[mt][nt][1] + bias2[nt][1], 0.f)) << 16);
                const uint u1 = (uint)f2bf(fmaxf(acc2[mt][nt][2] + bias2[nt][2], 0.f))
                              | ((uint)f2bf(fmaxf(acc2[mt][nt][3] + bias2[nt][3], 0.f)) << 16);
                const int chunk = (mt * 4 + w) * 64 + (2 * nt + (g >> 1)) * 16 + rc;
                uint2 val; val.x = u0; val.y = u1;
                *(uint2*)&A3[chunk * 8 + (g & 1) * 4] = val;
            }
        __syncthreads();   // A3 ready; A1 reads done

        // ---------- Phase D: layer 3 (128->256), fused pool ----------
        f32x4 acc3[4][4];
        #pragma unroll
        for (int mt = 0; mt < 4; ++mt)
            #pragma unroll
            for (int nt = 0; nt < 4; ++nt)
                acc3[mt][nt] = (f32x4){0.f, 0.f, 0.f, 0.f};

        #pragma unroll
        for (int ks = 0; ks < 4; ++ks) {
            bf16x8 bf[4];
            #pragma unroll
            for (int nt = 0; nt < 4; ++nt)
                bf[nt] = *(const bf16x8*)(B3P + (((4 * w + nt) * 4 + ks) * 64 + lane) * 8);
            #pragma unroll
            for (int mt = 0; mt < 4; ++mt) {
                const bf16x8 a = *(const bf16x8*)&A3[((mt * 4 + ks) * 64 + lane) * 8];
                #pragma unroll
                for (int nt = 0; nt < 4; ++nt)
                    acc3[mt][nt] = __builtin_amdgcn_mfma_f32_16x16x32_bf16(a, bf[nt], acc3[mt][nt], 0, 0, 0);
            }
        }
        #pragma unroll
        for (int nt = 0; nt < 4; ++nt)
            #pragma unroll
            for (int mt = 0; mt < 4; ++mt)
                #pragma unroll
                for (int rr = 0; rr < 4; ++rr)
                    pool[nt] = fmaxf(pool[nt], fmaxf(acc3[mt][nt][rr] + bias3v[nt], 0.f));
    }

    // cross-lane pool: combine the 4 row-groups
    #pragma unroll
    for (int nt = 0; nt < 4; ++nt) {
        pool[nt] = fmaxf(pool[nt], __shfl_xor(pool[nt], 16, 64));
        pool[nt] = fmaxf(pool[nt], __shfl_xor(pool[nt], 32, 64));
    }
    if (g == 0) {
        #pragma unroll
        for (int nt = 0; nt < 4; ++nt)
            featsS[w * 64 + nt * 16 + rc] = pool[nt];
    }
    __syncthreads();

    // ---------- heads: wave 0, 5 dot products of length 256 ----------
    if (tid < 64) {
        float c = 0.f, r0 = 0.f, r1 = 0.f, r2 = 0.f, r3 = 0.f;
        #pragma unroll
        for (int t4 = 0; t4 < 4; ++t4) {
            const int f = tid + 64 * t4;
            const float v = featsS[f];
            c  = fmaf(v, Wc[f], c);
            r0 = fmaf(v, Wr[f * 4 + 0], r0);
            r1 = fmaf(v, Wr[f * 4 + 1], r1);
            r2 = fmaf(v, Wr[f * 4 + 2], r2);
            r3 = fmaf(v, Wr[f * 4 + 3], r3);
        }
        #pragma unroll
        for (int off = 32; off > 0; off >>= 1) {
            c  += __shfl_xor(c,  off, 64);
            r0 += __shfl_xor(r0, off, 64);
            r1 += __shfl_xor(r1, off, 64);
            r2 += __shfl_xor(r2, off, 64);
            r3 += __shfl_xor(r3, off, 64);
        }
        if (tid == 0) {
            out[p]             = c  + bc[0];
            out[P + p * 4 + 0] = r0 + br[0];
            out[P + p * 4 + 1] = r1 + br[1];
            out[P + p * 4 + 2] = r2 + br[2];
            out[P + p * 4 + 3] = r3 + br[3];
        }
    }
}

extern "C" void kernel_launch(void* const* d_in, const int* in_sizes, int n_in,
                              void* d_out, int out_size, void* d_ws, size_t ws_size,
                              hipStream_t stream)
{
    const float* points    = (const float*)d_in[0];
    const int*   lengths   = (const int*)  d_in[1];
    const float* proposals = (const float*)d_in[2];
    const float* W1 = (const float*)d_in[3];
    const float* b1 = (const float*)d_in[4];
    const float* W2 = (const float*)d_in[5];
    const float* b2 = (const float*)d_in[6];
    const float* W3 = (const float*)d_in[7];
    const float* b3 = (const float*)d_in[8];
    const float* Wc = (const float*)d_in[9];
    const float* bc = (const float*)d_in[10];
    const float* Wr = (const float*)d_in[11];
    const float* br = (const float*)d_in[12];
    float* out = (float*)d_out;

    const int P = in_sizes[1];              // 2048
    const int N = in_sizes[0] / (3 * P);    // 256

    ushort* B2P = (ushort*)d_ws;            // 8192 bf16  (16 KB)
    ushort* B3P = B2P + 8192;               // 32768 bf16 (64 KB)

    pack_weights<<<dim3(128), dim3(256), 0, stream>>>(W2, W3, B2P, B3P);
    refine_mfma<<<dim3(P), dim3(256), 0, stream>>>(
        points, lengths, proposals, W1, b1, b2, b3, Wc, bc, Wr, br,
        B2P, B3P, out, P, N);
}

// Round 3
// 69.496 us; speedup vs baseline: 17.1677x; 1.2673x over previous
//
#include <hip/hip_runtime.h>

#define MIN_PTS 4

typedef short bf16x8 __attribute__((ext_vector_type(8)));
typedef float f32x4  __attribute__((ext_vector_type(4)));

__device__ __forceinline__ ushort f2bf(float x) {
    unsigned u = __float_as_uint(x);
    u = (u + 0x7fffu + ((u >> 16) & 1u)) >> 16;   // RNE, finite inputs
    return (ushort)u;
}

// Pack W2 [64][128] and W3 [128][256] (fp32 row-major, K x N) into bf16
// MFMA B-fragment-linear layout: [ntile][kstep][lane][8], where
// element j of lane l = W[k = 32*ks + 8*(l>>4) + j][col = 16*nt + (l&15)].
__global__ void pack_weights(const float* __restrict__ W2, const float* __restrict__ W3,
                             ushort* __restrict__ B2P, ushort* __restrict__ B3P)
{
    int idx = blockIdx.x * 256 + threadIdx.x;
    if (idx < 8192) {   // W2: 8 ntiles x 2 ksteps x 64 lanes x 8
        int j = idx & 7, l = (idx >> 3) & 63, ks = (idx >> 9) & 1, nt = idx >> 10;
        int k   = ks * 32 + (l >> 4) * 8 + j;
        int col = nt * 16 + (l & 15);
        B2P[idx] = f2bf(W2[k * 128 + col]);
    }
    if (idx < 32768) {  // W3: 16 ntiles x 4 ksteps x 64 lanes x 8
        int j = idx & 7, l = (idx >> 3) & 63, ks = (idx >> 9) & 3, nt = idx >> 11;
        int k   = ks * 32 + (l >> 4) * 8 + j;
        int col = nt * 16 + (l & 15);
        B3P[idx] = f2bf(W3[k * 256 + col]);
    }
}

// One block = one 64-point stripe of one proposal. Perfectly uniform work.
__global__ __launch_bounds__(256, 4) void refine_stripe(
    const float* __restrict__ points,    // [P][N][3]
    const int*   __restrict__ lengths,   // [P]
    const float* __restrict__ proposals, // [P][6]
    const float* __restrict__ W1, const float* __restrict__ b1,   // [3][64],[64]
    const float* __restrict__ b2,                                  // [128]
    const float* __restrict__ b3,                                  // [256]
    const ushort* __restrict__ B2P, const ushort* __restrict__ B3P,
    int* __restrict__ featsG,            // [P][256] f32 bits, pre-zeroed
    int P, int N)
{
    const int p   = blockIdx.x;
    const int s   = blockIdx.y;
    const int len = lengths[p];
    if (len < MIN_PTS || s * 64 >= len) return;   // feats stay 0 -> bias-only heads

    // A1: h1 fragments  [mtile(4)][kstep(2)][lane(64)][8] bf16  = 8 KB
    // A3: h2 fragments  [mtile(4)][kstep(4)][lane(64)][8] bf16  = 16 KB
    __shared__ __align__(16) ushort A1[4096];
    __shared__ __align__(16) ushort A3[8192];

    const int tid  = threadIdx.x;
    const int lane = tid & 63;
    const int w    = tid >> 6;      // wave id 0..3
    const int rc   = lane & 15;
    const int g    = lane >> 4;

    const float cx = proposals[p * 6 + 0];
    const float cy = proposals[p * 6 + 1];
    const float cz = proposals[p * 6 + 2];
    const float hx = fmaf(proposals[p * 6 + 3], 0.5f, 1e-6f);
    const float hy = fmaf(proposals[p * 6 + 4], 0.5f, 1e-6f);
    const float hz = fmaf(proposals[p * 6 + 5], 0.5f, 1e-6f);

    float bias2[2][4];
    #pragma unroll
    for (int nt = 0; nt < 2; ++nt)
        #pragma unroll
        for (int rr = 0; rr < 4; ++rr)
            bias2[nt][rr] = b2[32 * w + 16 * nt + 4 * g + rr];
    float bias3v[4];
    #pragma unroll
    for (int nt = 0; nt < 4; ++nt)
        bias3v[nt] = b3[64 * w + 16 * nt + rc];

    // ---------- Phase A: layer 1 (3->64) on VALU, write A1 fragments ----------
    {
        const int jj = min(s * 64 + lane, len - 1);     // duplicate last point (max-safe)
        const float* pt = points + (p * N + jj) * 3;
        const float x0 = (pt[0] - cx) / hx;
        const float x1 = (pt[1] - cy) / hy;
        const float x2 = (pt[2] - cz) / hz;

        union { ushort u[16]; uint4 q[2]; } t;
        #pragma unroll
        for (int i = 0; i < 16; ++i) {
            const int f = w * 16 + i;                   // wave w -> features 16w..16w+15
            float v = fmaf(x0, W1[f], fmaf(x1, W1[64 + f], fmaf(x2, W1[128 + f], b1[f])));
            t.u[i] = f2bf(fmaxf(v, 0.f));
        }
        const int mt = lane >> 4, r = lane & 15;
        #pragma unroll
        for (int c = 0; c < 2; ++c) {
            const int k0 = w * 16 + c * 8;
            const int ks = k0 >> 5, g2 = (k0 >> 3) & 3;
            const int chunk = (mt * 2 + ks) * 64 + g2 * 16 + r;
            *(uint4*)&A1[chunk * 8] = t.q[c];
        }
    }
    __syncthreads();

    // ---------- Phase B: layer 2 (64->128), swapped operands ----------
    {
        f32x4 acc2[4][2];
        #pragma unroll
        for (int mt = 0; mt < 4; ++mt)
            #pragma unroll
            for (int nt = 0; nt < 2; ++nt)
                acc2[mt][nt] = (f32x4){0.f, 0.f, 0.f, 0.f};

        #pragma unroll
        for (int ks = 0; ks < 2; ++ks) {
            const bf16x8 bw0 = *(const bf16x8*)(B2P + (((2 * w + 0) * 2 + ks) * 64 + lane) * 8);
            const bf16x8 bw1 = *(const bf16x8*)(B2P + (((2 * w + 1) * 2 + ks) * 64 + lane) * 8);
            #pragma unroll
            for (int mt = 0; mt < 4; ++mt) {
                const bf16x8 a = *(const bf16x8*)&A1[((mt * 2 + ks) * 64 + lane) * 8];
                acc2[mt][0] = __builtin_amdgcn_mfma_f32_16x16x32_bf16(bw0, a, acc2[mt][0], 0, 0, 0);
                acc2[mt][1] = __builtin_amdgcn_mfma_f32_16x16x32_bf16(bw1, a, acc2[mt][1], 0, 0, 0);
            }
        }
        // bias+relu, pack 4 consecutive k-features of one point -> ds_write_b64 into A3
        #pragma unroll
        for (int mt = 0; mt < 4; ++mt)
            #pragma unroll
            for (int nt = 0; nt < 2; ++nt) {
                const uint u0 = (uint)f2bf(fmaxf(acc2[mt][nt][0] + bias2[nt][0], 0.f))
                              | ((uint)f2bf(fmaxf(acc2[mt][nt][1] + bias2[nt][1], 0.f)) << 16);
                const uint u1 = (uint)f2bf(fmaxf(acc2[mt][nt][2] + bias2[nt][2], 0.f))
                              | ((uint)f2bf(fmaxf(acc2[mt][nt][3] + bias2[nt][3], 0.f)) << 16);
                const int chunk = (mt * 4 + w) * 64 + (2 * nt + (g >> 1)) * 16 + rc;
                uint2 val; val.x = u0; val.y = u1;
                *(uint2*)&A3[chunk * 8 + (g & 1) * 4] = val;
            }
    }
    __syncthreads();

    // ---------- Phase D: layer 3 (128->256) in two nt-halves, fused pool ----------
    float pool[4] = {0.f, 0.f, 0.f, 0.f};

    #pragma unroll 1
    for (int nh = 0; nh < 2; ++nh) {
        f32x4 acc3[4][2];
        #pragma unroll
        for (int mt = 0; mt < 4; ++mt)
            #pragma unroll
            for (int j = 0; j < 2; ++j)
                acc3[mt][j] = (f32x4){0.f, 0.f, 0.f, 0.f};

        #pragma unroll
        for (int ks = 0; ks < 4; ++ks) {
            const bf16x8 bf0 = *(const bf16x8*)(B3P + (((4 * w + 2 * nh + 0) * 4 + ks) * 64 + lane) * 8);
            const bf16x8 bf1 = *(const bf16x8*)(B3P + (((4 * w + 2 * nh + 1) * 4 + ks) * 64 + lane) * 8);
            #pragma unroll
            for (int mt = 0; mt < 4; ++mt) {
                const bf16x8 a = *(const bf16x8*)&A3[((mt * 4 + ks) * 64 + lane) * 8];
                acc3[mt][0] = __builtin_amdgcn_mfma_f32_16x16x32_bf16(a, bf0, acc3[mt][0], 0, 0, 0);
                acc3[mt][1] = __builtin_amdgcn_mfma_f32_16x16x32_bf16(a, bf1, acc3[mt][1], 0, 0, 0);
            }
        }
        #pragma unroll
        for (int j = 0; j < 2; ++j)
            #pragma unroll
            for (int mt = 0; mt < 4; ++mt)
                #pragma unroll
                for (int rr = 0; rr < 4; ++rr)
                    pool[2 * nh + j] = fmaxf(pool[2 * nh + j],
                                             fmaxf(acc3[mt][j][rr] + bias3v[2 * nh + j], 0.f));
    }

    // pool across the 4 row-groups, then merge into global feats (int-bit max, vals >= 0)
    #pragma unroll
    for (int nt = 0; nt < 4; ++nt) {
        pool[nt] = fmaxf(pool[nt], __shfl_xor(pool[nt], 16, 64));
        pool[nt] = fmaxf(pool[nt], __shfl_xor(pool[nt], 32, 64));
    }
    if (g == 0) {
        #pragma unroll
        for (int nt = 0; nt < 4; ++nt)
            atomicMax(&featsG[p * 256 + w * 64 + nt * 16 + rc], __float_as_int(pool[nt]));
    }
}

// One wave per proposal: 5 dot products of length 256.
__global__ __launch_bounds__(256) void heads_kernel(
    const int* __restrict__ featsG,
    const float* __restrict__ Wc, const float* __restrict__ bc,
    const float* __restrict__ Wr, const float* __restrict__ br,
    float* __restrict__ out, int P)
{
    const int tid  = threadIdx.x;
    const int lane = tid & 63;
    const int p    = blockIdx.x * 4 + (tid >> 6);
    if (p >= P) return;

    const int4 vi = *(const int4*)&featsG[p * 256 + lane * 4];
    float v[4] = {__int_as_float(vi.x), __int_as_float(vi.y),
                  __int_as_float(vi.z), __int_as_float(vi.w)};

    const float4 wc = *(const float4*)&Wc[lane * 4];
    float c  = v[0] * wc.x + v[1] * wc.y + v[2] * wc.z + v[3] * wc.w;
    float r0 = 0.f, r1 = 0.f, r2 = 0.f, r3 = 0.f;
    #pragma unroll
    for (int i = 0; i < 4; ++i) {
        const float4 wr = *(const float4*)&Wr[(lane * 4 + i) * 4];
        r0 = fmaf(v[i], wr.x, r0);
        r1 = fmaf(v[i], wr.y, r1);
        r2 = fmaf(v[i], wr.z, r2);
        r3 = fmaf(v[i], wr.w, r3);
    }
    #pragma unroll
    for (int off = 32; off > 0; off >>= 1) {
        c  += __shfl_xor(c,  off, 64);
        r0 += __shfl_xor(r0, off, 64);
        r1 += __shfl_xor(r1, off, 64);
        r2 += __shfl_xor(r2, off, 64);
        r3 += __shfl_xor(r3, off, 64);
    }
    if (lane == 0) {
        out[p]             = c  + bc[0];
        out[P + p * 4 + 0] = r0 + br[0];
        out[P + p * 4 + 1] = r1 + br[1];
        out[P + p * 4 + 2] = r2 + br[2];
        out[P + p * 4 + 3] = r3 + br[3];
    }
}

extern "C" void kernel_launch(void* const* d_in, const int* in_sizes, int n_in,
                              void* d_out, int out_size, void* d_ws, size_t ws_size,
                              hipStream_t stream)
{
    const float* points    = (const float*)d_in[0];
    const int*   lengths   = (const int*)  d_in[1];
    const float* proposals = (const float*)d_in[2];
    const float* W1 = (const float*)d_in[3];
    const float* b1 = (const float*)d_in[4];
    const float* W2 = (const float*)d_in[5];
    const float* b2 = (const float*)d_in[6];
    const float* W3 = (const float*)d_in[7];
    const float* b3 = (const float*)d_in[8];
    const float* Wc = (const float*)d_in[9];
    const float* bc = (const float*)d_in[10];
    const float* Wr = (const float*)d_in[11];
    const float* br = (const float*)d_in[12];
    float* out = (float*)d_out;

    const int P = in_sizes[1];              // 2048
    const int N = in_sizes[0] / (3 * P);    // 256
    const int SMAX = (N + 63) / 64;         // 4

    ushort* B2P    = (ushort*)d_ws;                 // 8192 bf16  (16 KB)
    ushort* B3P    = B2P + 8192;                    // 32768 bf16 (64 KB)
    int*    featsG = (int*)((char*)d_ws + 81920);   // P*256 ints (2 MB)

    hipMemsetAsync(featsG, 0, (size_t)P * 256 * sizeof(int), stream);
    pack_weights<<<dim3(128), dim3(256), 0, stream>>>(W2, W3, B2P, B3P);
    refine_stripe<<<dim3(P, SMAX), dim3(256), 0, stream>>>(
        points, lengths, proposals, W1, b1, b2, b3, B2P, B3P, featsG, P, N);
    heads_kernel<<<dim3((P + 3) / 4), dim3(256), 0, stream>>>(
        featsG, Wc, bc, Wr, br, out, P);
}

// Round 4
// 50.043 us; speedup vs baseline: 23.8413x; 1.3887x over previous
//
#include <hip/hip_runtime.h>

#define MIN_PTS 4

typedef short bf16x8 __attribute__((ext_vector_type(8)));
typedef float f32x4  __attribute__((ext_vector_type(4)));

__device__ __forceinline__ ushort f2bf(float x) {
    unsigned u = __float_as_uint(x);
    u = (u + 0x7fffu + ((u >> 16) & 1u)) >> 16;   // RNE, finite inputs
    return (ushort)u;
}

// Pack W2 [64][128] and W3 [128][256] (fp32 row-major, K x N) into bf16
// MFMA B-fragment-linear layout: [ntile][kstep][lane][8], where
// element j of lane l = W[k = 32*ks + 8*(l>>4) + j][col = 16*nt + (l&15)].
__global__ void pack_weights(const float* __restrict__ W2, const float* __restrict__ W3,
                             ushort* __restrict__ B2P, ushort* __restrict__ B3P)
{
    int idx = blockIdx.x * 256 + threadIdx.x;
    if (idx < 8192) {   // W2: 8 ntiles x 2 ksteps x 64 lanes x 8
        int j = idx & 7, l = (idx >> 3) & 63, ks = (idx >> 9) & 1, nt = idx >> 10;
        int k   = ks * 32 + (l >> 4) * 8 + j;
        int col = nt * 16 + (l & 15);
        B2P[idx] = f2bf(W2[k * 128 + col]);
    }
    if (idx < 32768) {  // W3: 16 ntiles x 4 ksteps x 64 lanes x 8
        int j = idx & 7, l = (idx >> 3) & 63, ks = (idx >> 9) & 3, nt = idx >> 11;
        int k   = ks * 32 + (l >> 4) * 8 + j;
        int col = nt * 16 + (l & 15);
        B3P[idx] = f2bf(W3[k * 256 + col]);
    }
}

// One block (8 waves, 512 thr) = one 64-point stripe of one proposal.
// Wave w: layer1 features 8w..8w+7; layer2 ntile w; layer3 ntiles {2w, 2w+1}.
__global__ __launch_bounds__(512, 8) void refine_stripe(
    const float* __restrict__ points,    // [P][N][3]
    const int*   __restrict__ lengths,   // [P]
    const float* __restrict__ proposals, // [P][6]
    const float* __restrict__ W1, const float* __restrict__ b1,   // [3][64],[64]
    const float* __restrict__ b2,                                  // [128]
    const float* __restrict__ b3,                                  // [256]
    const ushort* __restrict__ B2P, const ushort* __restrict__ B3P,
    int* __restrict__ featsG,            // [P][256] f32 bits, pre-zeroed
    int P, int N)
{
    const int p   = blockIdx.x;
    const int s   = blockIdx.y;
    const int len = lengths[p];
    if (len < MIN_PTS || s * 64 >= len) return;   // feats stay 0 -> bias-only heads

    // A1: h1 fragments  [mtile(4)][kstep(2)][lane(64)][8] bf16  = 8 KB
    // A3: h2 fragments  [mtile(4)][kstep(4)][lane(64)][8] bf16  = 16 KB
    __shared__ __align__(16) ushort A1[4096];
    __shared__ __align__(16) ushort A3[8192];

    const int tid  = threadIdx.x;
    const int lane = tid & 63;
    const int w    = tid >> 6;      // wave id 0..7
    const int rc   = lane & 15;
    const int g    = lane >> 4;

    const float cx = proposals[p * 6 + 0];
    const float cy = proposals[p * 6 + 1];
    const float cz = proposals[p * 6 + 2];
    const float rhx = __builtin_amdgcn_rcpf(fmaf(proposals[p * 6 + 3], 0.5f, 1e-6f));
    const float rhy = __builtin_amdgcn_rcpf(fmaf(proposals[p * 6 + 4], 0.5f, 1e-6f));
    const float rhz = __builtin_amdgcn_rcpf(fmaf(proposals[p * 6 + 5], 0.5f, 1e-6f));

    // ---------- Phase A: layer 1 (3->64) on VALU, one uint4 LDS write/lane ----------
    {
        const int jj = min(s * 64 + lane, len - 1);     // duplicate last point (max-safe)
        const float* pt = points + (p * N + jj) * 3;
        const float x0 = (pt[0] - cx) * rhx;
        const float x1 = (pt[1] - cy) * rhy;
        const float x2 = (pt[2] - cz) * rhz;

        union { ushort u[8]; uint4 q; } t;
        #pragma unroll
        for (int i = 0; i < 8; ++i) {
            const int f = w * 8 + i;                    // wave w -> features 8w..8w+7
            float v = fmaf(x0, W1[f], fmaf(x1, W1[64 + f], fmaf(x2, W1[128 + f], b1[f])));
            t.u[i] = f2bf(fmaxf(v, 0.f));
        }
        // fragment slot: k0 = 8w -> ks = w>>2, lane-group g2 = w&3
        const int mt = lane >> 4, r = lane & 15;
        const int chunk = (mt * 2 + (w >> 2)) * 64 + (w & 3) * 16 + r;
        *(uint4*)&A1[chunk * 8] = t.q;
    }
    __syncthreads();

    // ---------- Phase B: layer 2 (64->128), swapped operands, ntile = w ----------
    {
        f32x4 acc2[4];
        #pragma unroll
        for (int mt = 0; mt < 4; ++mt) acc2[mt] = (f32x4){0.f, 0.f, 0.f, 0.f};

        #pragma unroll
        for (int ks = 0; ks < 2; ++ks) {
            const bf16x8 bw = *(const bf16x8*)(B2P + ((w * 2 + ks) * 64 + lane) * 8);
            #pragma unroll
            for (int mt = 0; mt < 4; ++mt) {
                const bf16x8 a = *(const bf16x8*)&A1[((mt * 2 + ks) * 64 + lane) * 8];
                acc2[mt] = __builtin_amdgcn_mfma_f32_16x16x32_bf16(bw, a, acc2[mt], 0, 0, 0);
            }
        }
        // D: feature = 16w + 4g + rr, point = 16mt + rc.
        // bias + relu, pack 4 consecutive layer-3 k's of one point -> ds_write_b64
        float bias2v[4];
        #pragma unroll
        for (int rr = 0; rr < 4; ++rr) bias2v[rr] = b2[16 * w + 4 * g + rr];

        const int ks3 = w >> 1;                      // (16w+4g)>>5
        const int g3  = (2 * w + (g >> 1)) & 3;      // ((16w+4g)>>3)&3
        #pragma unroll
        for (int mt = 0; mt < 4; ++mt) {
            const uint u0 = (uint)f2bf(fmaxf(acc2[mt][0] + bias2v[0], 0.f))
                          | ((uint)f2bf(fmaxf(acc2[mt][1] + bias2v[1], 0.f)) << 16);
            const uint u1 = (uint)f2bf(fmaxf(acc2[mt][2] + bias2v[2], 0.f))
                          | ((uint)f2bf(fmaxf(acc2[mt][3] + bias2v[3], 0.f)) << 16);
            const int chunk = (mt * 4 + ks3) * 64 + g3 * 16 + rc;
            uint2 val; val.x = u0; val.y = u1;
            *(uint2*)&A3[chunk * 8 + (g & 1) * 4] = val;
        }
    }
    __syncthreads();

    // ---------- Phase D: layer 3 (128->256), ntiles {2w, 2w+1}, fused pool ----------
    {
        f32x4 acc3[4][2];
        #pragma unroll
        for (int mt = 0; mt < 4; ++mt)
            #pragma unroll
            for (int j = 0; j < 2; ++j)
                acc3[mt][j] = (f32x4){0.f, 0.f, 0.f, 0.f};

        #pragma unroll
        for (int ks = 0; ks < 4; ++ks) {
            const bf16x8 bf0 = *(const bf16x8*)(B3P + (((2 * w + 0) * 4 + ks) * 64 + lane) * 8);
            const bf16x8 bf1 = *(const bf16x8*)(B3P + (((2 * w + 1) * 4 + ks) * 64 + lane) * 8);
            #pragma unroll
            for (int mt = 0; mt < 4; ++mt) {
                const bf16x8 a = *(const bf16x8*)&A3[((mt * 4 + ks) * 64 + lane) * 8];
                acc3[mt][0] = __builtin_amdgcn_mfma_f32_16x16x32_bf16(a, bf0, acc3[mt][0], 0, 0, 0);
                acc3[mt][1] = __builtin_amdgcn_mfma_f32_16x16x32_bf16(a, bf1, acc3[mt][1], 0, 0, 0);
            }
        }

        float pool[2];
        #pragma unroll
        for (int j = 0; j < 2; ++j) {
            const float b3v = b3[16 * (2 * w + j) + rc];
            float m = 0.f;
            #pragma unroll
            for (int mt = 0; mt < 4; ++mt)
                #pragma unroll
                for (int rr = 0; rr < 4; ++rr)
                    m = fmaxf(m, acc3[mt][j][rr] + b3v);
            pool[j] = m;   // relu folded: max with 0 init
        }
        // pool across the 4 row-groups, then merge into global feats (int-bit max)
        #pragma unroll
        for (int j = 0; j < 2; ++j) {
            pool[j] = fmaxf(pool[j], __shfl_xor(pool[j], 16, 64));
            pool[j] = fmaxf(pool[j], __shfl_xor(pool[j], 32, 64));
        }
        if (g == 0) {
            #pragma unroll
            for (int j = 0; j < 2; ++j)
                atomicMax(&featsG[p * 256 + (2 * w + j) * 16 + rc], __float_as_int(pool[j]));
        }
    }
}

// One wave per proposal: 5 dot products of length 256.
__global__ __launch_bounds__(256) void heads_kernel(
    const int* __restrict__ featsG,
    const float* __restrict__ Wc, const float* __restrict__ bc,
    const float* __restrict__ Wr, const float* __restrict__ br,
    float* __restrict__ out, int P)
{
    const int tid  = threadIdx.x;
    const int lane = tid & 63;
    const int p    = blockIdx.x * 4 + (tid >> 6);
    if (p >= P) return;

    const int4 vi = *(const int4*)&featsG[p * 256 + lane * 4];
    float v[4] = {__int_as_float(vi.x), __int_as_float(vi.y),
                  __int_as_float(vi.z), __int_as_float(vi.w)};

    const float4 wc = *(const float4*)&Wc[lane * 4];
    float c  = v[0] * wc.x + v[1] * wc.y + v[2] * wc.z + v[3] * wc.w;
    float r0 = 0.f, r1 = 0.f, r2 = 0.f, r3 = 0.f;
    #pragma unroll
    for (int i = 0; i < 4; ++i) {
        const float4 wr = *(const float4*)&Wr[(lane * 4 + i) * 4];
        r0 = fmaf(v[i], wr.x, r0);
        r1 = fmaf(v[i], wr.y, r1);
        r2 = fmaf(v[i], wr.z, r2);
        r3 = fmaf(v[i], wr.w, r3);
    }
    #pragma unroll
    for (int off = 32; off > 0; off >>= 1) {
        c  += __shfl_xor(c,  off, 64);
        r0 += __shfl_xor(r0, off, 64);
        r1 += __shfl_xor(r1, off, 64);
        r2 += __shfl_xor(r2, off, 64);
        r3 += __shfl_xor(r3, off, 64);
    }
    if (lane == 0) {
        out[p]             = c  + bc[0];
        out[P + p * 4 + 0] = r0 + br[0];
        out[P + p * 4 + 1] = r1 + br[1];
        out[P + p * 4 + 2] = r2 + br[2];
        out[P + p * 4 + 3] = r3 + br[3];
    }
}

extern "C" void kernel_launch(void* const* d_in, const int* in_sizes, int n_in,
                              void* d_out, int out_size, void* d_ws, size_t ws_size,
                              hipStream_t stream)
{
    const float* points    = (const float*)d_in[0];
    const int*   lengths   = (const int*)  d_in[1];
    const float* proposals = (const float*)d_in[2];
    const float* W1 = (const float*)d_in[3];
    const float* b1 = (const float*)d_in[4];
    const float* W2 = (const float*)d_in[5];
    const float* b2 = (const float*)d_in[6];
    const float* W3 = (const float*)d_in[7];
    const float* b3 = (const float*)d_in[8];
    const float* Wc = (const float*)d_in[9];
    const float* bc = (const float*)d_in[10];
    const float* Wr = (const float*)d_in[11];
    const float* br = (const float*)d_in[12];
    float* out = (float*)d_out;

    const int P = in_sizes[1];              // 2048
    const int N = in_sizes[0] / (3 * P);    // 256
    const int SMAX = (N + 63) / 64;         // 4

    ushort* B2P    = (ushort*)d_ws;                 // 8192 bf16  (16 KB)
    ushort* B3P    = B2P + 8192;                    // 32768 bf16 (64 KB)
    int*    featsG = (int*)((char*)d_ws + 81920);   // P*256 ints (2 MB)

    hipMemsetAsync(featsG, 0, (size_t)P * 256 * sizeof(int), stream);
    pack_weights<<<dim3(128), dim3(256), 0, stream>>>(W2, W3, B2P, B3P);
    refine_stripe<<<dim3(P, SMAX), dim3(512), 0, stream>>>(
        points, lengths, proposals, W1, b1, b2, b3, B2P, B3P, featsG, P, N);
    heads_kernel<<<dim3((P + 3) / 4), dim3(256), 0, stream>>>(
        featsG, Wc, bc, Wr, br, out, P);
}